// Round 1
// baseline (107.041 us; speedup 1.0000x reference)
//
#include <hip/hip_runtime.h>

// GEMV: out[o] = sum_i x[i] * W[o*N_IN + i] + b[o]
// x: (1, 147456) f32, W: (1000, 147456) f32, b: (1000,) f32, out: (1, 1000) f32.
// Memory-bound: W is ~590 MB per pass -> floor ~94 us @ 6.3 TB/s.

#define N_IN 147456
#define N_CLASSES 1000

__global__ __launch_bounds__(256) void gemv_rowblock(
    const float* __restrict__ x,
    const float* __restrict__ W,
    const float* __restrict__ b,
    float* __restrict__ out)
{
    const int o = blockIdx.x;
    if (o >= N_CLASSES) return;

    const float4* __restrict__ Wrow =
        reinterpret_cast<const float4*>(W + (size_t)o * N_IN);
    const float4* __restrict__ xv = reinterpret_cast<const float4*>(x);

    const int nvec = N_IN / 4;  // 36864, divisible by 256 (144 iters/thread)
    float acc = 0.0f;
    for (int i = threadIdx.x; i < nvec; i += 256) {
        float4 wv = Wrow[i];
        float4 xx = xv[i];
        acc += wv.x * xx.x;
        acc += wv.y * xx.y;
        acc += wv.z * xx.z;
        acc += wv.w * xx.w;
    }

    // 64-lane wave reduction
    #pragma unroll
    for (int off = 32; off > 0; off >>= 1)
        acc += __shfl_down(acc, off, 64);

    __shared__ float s[4];
    const int wid  = threadIdx.x >> 6;
    const int lane = threadIdx.x & 63;
    if (lane == 0) s[wid] = acc;
    __syncthreads();

    if (threadIdx.x == 0) {
        float t = s[0] + s[1] + s[2] + s[3];
        out[o] = t + b[o];
    }
}

extern "C" void kernel_launch(void* const* d_in, const int* in_sizes, int n_in,
                              void* d_out, int out_size, void* d_ws, size_t ws_size,
                              hipStream_t stream) {
    const float* x = (const float*)d_in[0];
    const float* W = (const float*)d_in[1];
    const float* b = (const float*)d_in[2];
    float* out = (float*)d_out;

    gemv_rowblock<<<N_CLASSES, 256, 0, stream>>>(x, W, b, out);
}